// Round 1
// baseline (700.229 us; speedup 1.0000x reference)
//
#include <hip/hip_runtime.h>
#include <math.h>

#define DD   128
#define HH   8
#define NQKV 384
#define GM   32

// ---------------- utility kernels ----------------
__global__ void zero_i32_kernel(int* __restrict__ p, int n) {
    int i = blockIdx.x * blockDim.x + threadIdx.x;
    if (i < n) p[i] = 0;
}

__global__ void hist_kernel(const int* __restrict__ dst, int* __restrict__ counts, int E) {
    int e = blockIdx.x * blockDim.x + threadIdx.x;
    if (e < E) atomicAdd(&counts[dst[e]], 1);
}

__global__ void scan_partial_kernel(const int* __restrict__ in, int* __restrict__ out,
                                    int* __restrict__ bsums, int n) {
    __shared__ int s[256];
    int tid = threadIdx.x;
    int gid = blockIdx.x * 256 + tid;
    int v = (gid < n) ? in[gid] : 0;
    s[tid] = v;
    __syncthreads();
    for (int off = 1; off < 256; off <<= 1) {
        int t = (tid >= off) ? s[tid - off] : 0;
        __syncthreads();
        s[tid] += t;
        __syncthreads();
    }
    if (gid < n) out[gid] = s[tid] - v;      // exclusive
    if (tid == 255) bsums[blockIdx.x] = s[255];
}

__global__ void scan_sums_kernel(int* __restrict__ bs, int nb) {
    __shared__ int s[256];
    int tid = threadIdx.x;
    int v = (tid < nb) ? bs[tid] : 0;
    s[tid] = v;
    __syncthreads();
    for (int off = 1; off < 256; off <<= 1) {
        int t = (tid >= off) ? s[tid - off] : 0;
        __syncthreads();
        s[tid] += t;
        __syncthreads();
    }
    if (tid < nb) bs[tid] = s[tid] - v;      // exclusive, in place
}

__global__ void scan_add_kernel(int* __restrict__ offs, const int* __restrict__ bs,
                                int* __restrict__ cursor, int n) {
    int gid = blockIdx.x * blockDim.x + threadIdx.x;
    if (gid < n) {
        int o = offs[gid] + bs[gid >> 8];
        offs[gid]   = o;
        cursor[gid] = o;
    }
}

__global__ void scatter_kernel(const int* __restrict__ src, const int* __restrict__ dst,
                               int* __restrict__ cursor, int* __restrict__ csr_src, int E) {
    int e = blockIdx.x * blockDim.x + threadIdx.x;
    if (e < E) {
        int pos = atomicAdd(&cursor[dst[e]], 1);
        csr_src[pos] = src[e];
    }
}

// ---------------- GEMM: C[M][Nout] = A[M][128] @ B[Nout][128]^T + bias ----------------
// 128 threads/block; thread owns one output column j with B[j][:] in 32 float4 regs.
// A tile (GM x 128) in LDS, read as same-address broadcast ds_read_b128 (conflict-free).
__global__ __launch_bounds__(128) void gemm_regB_kernel(
    const float* __restrict__ A, const float* __restrict__ B,
    const float* __restrict__ bias, float* __restrict__ C,
    int M, int Nout)
{
    __shared__ float As[GM][DD];            // 16 KB
    const int tid = threadIdx.x;
    const int m0  = blockIdx.x * GM;
    const int j   = blockIdx.y * 128 + tid; // grid sized so j < Nout always

    // B row -> registers (32 float4 = 128 VGPRs)
    float4 Breg[32];
    const float4* Bp = (const float4*)(B + (size_t)j * DD);
    #pragma unroll
    for (int i = 0; i < 32; ++i) Breg[i] = Bp[i];

    // A tile -> LDS, coalesced float4
    #pragma unroll
    for (int i = 0; i < 8; ++i) {
        int idx = tid + i * 128;            // 0..1023 float4 slots
        int row = idx >> 5;                 // 0..31
        int c4  = idx & 31;                 // 0..31
        int m   = m0 + row;
        float4 v = (m < M) ? ((const float4*)(A + (size_t)m * DD))[c4]
                           : make_float4(0.f, 0.f, 0.f, 0.f);
        *(float4*)&As[row][c4 * 4] = v;
    }
    __syncthreads();

    const float4* As4 = (const float4*)As;
    const float bj = bias[j];

    for (int m = 0; m < GM; ++m) {
        float ax = 0.f, ay = 0.f, az = 0.f, aw = 0.f;  // 4 independent FMA chains
        #pragma unroll
        for (int k4 = 0; k4 < 32; ++k4) {
            float4 a = As4[m * 32 + k4];    // broadcast: all lanes same address
            float4 b = Breg[k4];
            ax += a.x * b.x;
            ay += a.y * b.y;
            az += a.z * b.z;
            aw += a.w * b.w;
        }
        int mm = m0 + m;
        if (mm < M) C[(size_t)mm * Nout + j] = (ax + ay) + (az + aw) + bj;
    }
}

// ---------------- per-node fused attention ----------------
// One block (128 threads) per destination node. qkv row layout per node:
// head h: q at [h*48 .. +15], k at [h*48+16 .. +31], v at [h*48+32 .. +47].
__global__ __launch_bounds__(128) void node_attn_kernel(
    const float* __restrict__ qkv, const int* __restrict__ csr_src,
    const int* __restrict__ offsets, const int* __restrict__ counts,
    float* __restrict__ agg, int N)
{
    const int n = blockIdx.x;
    const int t = threadIdx.x;

    __shared__ int   srcs_s[16];
    __shared__ float ss[16][8];             // [edge][head]

    const int row0 = offsets[n];
    const int deg  = counts[n];

    // phase-A mapping: (edge eA, head hA); preload q for this head
    const int hA = t & 7, eA = t >> 3;
    const float4* qp = (const float4*)(qkv + (size_t)n * NQKV + hA * 48);
    const float4 q0 = qp[0], q1 = qp[1], q2 = qp[2], q3 = qp[3];

    // phase-B mapping: (head hB, dim d)
    const int hB = t >> 4, d = t & 15;

    float m_run = -__builtin_inff();
    float l_run = 0.f;
    float acc   = 0.f;

    for (int c = 0; c < deg; c += 16) {
        __syncthreads();                    // protect srcs_s/ss from previous iter readers
        if (t < 16 && c + t < deg) srcs_s[t] = csr_src[row0 + c + t];
        __syncthreads();

        // ---- phase A: scores ----
        float s = -__builtin_inff();
        if (c + eA < deg) {
            int sv = srcs_s[eA];
            const float4* kp = (const float4*)(qkv + (size_t)sv * NQKV + hA * 48 + 16);
            float4 k0 = kp[0], k1 = kp[1], k2 = kp[2], k3 = kp[3];
            s = k0.x*q0.x + k0.y*q0.y + k0.z*q0.z + k0.w*q0.w
              + k1.x*q1.x + k1.y*q1.y + k1.z*q1.z + k1.w*q1.w
              + k2.x*q2.x + k2.y*q2.y + k2.z*q2.z + k2.w*q2.w
              + k3.x*q3.x + k3.y*q3.y + k3.z*q3.z + k3.w*q3.w;
            s *= 0.25f;                     // 1/sqrt(16)
        }
        ss[eA][hA] = s;
        __syncthreads();

        // ---- phase B: online softmax + V aggregation ----
        int cnt = min(16, deg - c);
        float cmax = -__builtin_inff();
        for (int i = 0; i < cnt; ++i) cmax = fmaxf(cmax, ss[i][hB]);
        float m_new = fmaxf(m_run, cmax);
        float scale = __expf(m_run - m_new);    // first iter: exp(-inf)=0
        acc   *= scale;
        l_run *= scale;
        for (int i = 0; i < cnt; ++i) {
            float p = __expf(ss[i][hB] - m_new);
            l_run += p;
            int sv = srcs_s[i];
            acc += p * qkv[(size_t)sv * NQKV + hB * 48 + 32 + d];
        }
        m_run = m_new;
    }

    // deg==0: acc=0, l_run=0 -> 0 (matches reference: empty segment -> agg 0)
    agg[(size_t)n * DD + t] = acc / fmaxf(l_run, 1e-30f);
}

// ---------------- launch ----------------
extern "C" void kernel_launch(void* const* d_in, const int* in_sizes, int n_in,
                              void* d_out, int out_size, void* d_ws, size_t ws_size,
                              hipStream_t stream) {
    const float* x     = (const float*)d_in[0];
    const int*   src   = (const int*)  d_in[1];
    const int*   dst   = (const int*)  d_in[2];
    const float* w_qkv = (const float*)d_in[3];
    const float* b_qkv = (const float*)d_in[4];
    const float* w_out = (const float*)d_in[5];
    const float* b_out = (const float*)d_in[6];
    float* out = (float*)d_out;

    const int N = in_sizes[0] / DD;   // 50000
    const int E = in_sizes[1];        // 800000

    char* ws = (char*)d_ws;
    float* qkv    = (float*)ws;  ws += (size_t)N * NQKV * sizeof(float); // 76.8 MB
    int* counts   = (int*)ws;    ws += (size_t)N * sizeof(int);
    int* offsets  = (int*)ws;    ws += (size_t)N * sizeof(int);
    int* cursor   = (int*)ws;    ws += (size_t)N * sizeof(int);
    int* bsums    = (int*)ws;    ws += 256 * sizeof(int);
    int* csr_src  = (int*)ws;    ws += (size_t)E * sizeof(int);
    float* agg    = (float*)ws;  ws += (size_t)N * DD * sizeof(float);   // 25.6 MB

    const int nb  = (N + 255) / 256;   // 196 (<=256 so single-block scan of bsums works)
    const int neb = (E + 255) / 256;

    // CSR build (by dst)
    zero_i32_kernel <<<nb, 256, 0, stream>>>(counts, N);
    hist_kernel     <<<neb, 256, 0, stream>>>(dst, counts, E);
    scan_partial_kernel<<<nb, 256, 0, stream>>>(counts, offsets, bsums, N);
    scan_sums_kernel<<<1, 256, 0, stream>>>(bsums, nb);
    scan_add_kernel <<<nb, 256, 0, stream>>>(offsets, bsums, cursor, N);
    scatter_kernel  <<<neb, 256, 0, stream>>>(src, dst, cursor, csr_src, E);

    // QKV projection: qkv = x @ w_qkv^T + b_qkv   (Nout=384 -> grid.y=3)
    gemm_regB_kernel<<<dim3((N + GM - 1) / GM, 3), 128, 0, stream>>>(
        x, w_qkv, b_qkv, qkv, N, NQKV);

    // fused per-node softmax-attention aggregation
    node_attn_kernel<<<N, 128, 0, stream>>>(qkv, csr_src, offsets, counts, agg, N);

    // output projection: out = agg @ w_out^T + b_out
    gemm_regB_kernel<<<dim3((N + GM - 1) / GM, 1), 128, 0, stream>>>(
        agg, w_out, b_out, out, N, DD);
}

// Round 2
// 468.148 us; speedup vs baseline: 1.4957x; 1.4957x over previous
//
#include <hip/hip_runtime.h>
#include <math.h>

#define DD   128
#define HH   8
#define NQKV 384

// ---------------- utility kernels ----------------
__global__ void zero_i32_kernel(int* __restrict__ p, int n) {
    int i = blockIdx.x * blockDim.x + threadIdx.x;
    if (i < n) p[i] = 0;
}

__global__ void hist_kernel(const int* __restrict__ dst, int* __restrict__ counts, int E) {
    int e = blockIdx.x * blockDim.x + threadIdx.x;
    if (e < E) atomicAdd(&counts[dst[e]], 1);
}

__global__ void scan_partial_kernel(const int* __restrict__ in, int* __restrict__ out,
                                    int* __restrict__ bsums, int n) {
    __shared__ int s[256];
    int tid = threadIdx.x;
    int gid = blockIdx.x * 256 + tid;
    int v = (gid < n) ? in[gid] : 0;
    s[tid] = v;
    __syncthreads();
    for (int off = 1; off < 256; off <<= 1) {
        int t = (tid >= off) ? s[tid - off] : 0;
        __syncthreads();
        s[tid] += t;
        __syncthreads();
    }
    if (gid < n) out[gid] = s[tid] - v;      // exclusive
    if (tid == 255) bsums[blockIdx.x] = s[255];
}

__global__ void scan_sums_kernel(int* __restrict__ bs, int nb) {
    __shared__ int s[256];
    int tid = threadIdx.x;
    int v = (tid < nb) ? bs[tid] : 0;
    s[tid] = v;
    __syncthreads();
    for (int off = 1; off < 256; off <<= 1) {
        int t = (tid >= off) ? s[tid - off] : 0;
        __syncthreads();
        s[tid] += t;
        __syncthreads();
    }
    if (tid < nb) bs[tid] = s[tid] - v;      // exclusive, in place
}

__global__ void scan_add_kernel(int* __restrict__ offs, const int* __restrict__ bs,
                                int* __restrict__ cursor, int n) {
    int gid = blockIdx.x * blockDim.x + threadIdx.x;
    if (gid < n) {
        int o = offs[gid] + bs[gid >> 8];
        offs[gid]   = o;
        cursor[gid] = o;
    }
}

__global__ void scatter_kernel(const int* __restrict__ src, const int* __restrict__ dst,
                               int* __restrict__ cursor, int* __restrict__ csr_src, int E) {
    int e = blockIdx.x * blockDim.x + threadIdx.x;
    if (e < E) {
        int pos = atomicAdd(&cursor[dst[e]], 1);
        csr_src[pos] = src[e];
    }
}

// ---------------- tiled SGEMM: C[M][Nout] = A[M][128] @ B[Nout][128]^T + bias -------
// 256 threads, 128x128 block tile, TK=32, 8x8 micro-tile per thread.
// A,B staged transposed in LDS: As[k][m], Bs[k][n] -> float4 fragment reads.
#define TM 128
#define TN 128
#define TK 32

__global__ __launch_bounds__(256, 2) void sgemm_kernel(
    const float* __restrict__ A, const float* __restrict__ B,
    const float* __restrict__ bias, float* __restrict__ C,
    int M, int Nout)
{
    __shared__ float As[TK][TM];   // 16 KB
    __shared__ float Bs[TK][TN];   // 16 KB

    const int tid = threadIdx.x;
    const int tx  = tid & 15;      // col group  (8 cols each)
    const int ty  = tid >> 4;      // row group  (8 rows each)
    const int m0  = blockIdx.x * TM;
    const int n0  = blockIdx.y * TN;

    // staging coords: r = row in tile (wave-distinct -> conflict-free LDS writes)
    const int sr  = tid & 127;           // 0..127
    const int sc0 = tid >> 7;            // 0..1

    float acc[8][8];
    #pragma unroll
    for (int i = 0; i < 8; ++i)
        #pragma unroll
        for (int j = 0; j < 8; ++j) acc[i][j] = 0.f;

    const int am = m0 + sr;
    const int bn = n0 + sr;
    const float4* Arow = (const float4*)(A + (size_t)am * DD);
    const float4* Brow = (const float4*)(B + (size_t)bn * DD);
    const bool a_ok = (am < M);
    const bool b_ok = (bn < Nout);

    for (int kc = 0; kc < DD; kc += TK) {
        const int kc4 = kc >> 2;
        // each thread stages 4 float4 of A and 4 of B (1024 slots / 256 thr)
        #pragma unroll
        for (int i = 0; i < 4; ++i) {
            int c4 = sc0 + 2 * i;        // 0..7
            float4 va = a_ok ? Arow[kc4 + c4] : make_float4(0.f,0.f,0.f,0.f);
            float4 vb = b_ok ? Brow[kc4 + c4] : make_float4(0.f,0.f,0.f,0.f);
            int k = c4 * 4;
            As[k+0][sr] = va.x; As[k+1][sr] = va.y; As[k+2][sr] = va.z; As[k+3][sr] = va.w;
            Bs[k+0][sr] = vb.x; Bs[k+1][sr] = vb.y; Bs[k+2][sr] = vb.z; Bs[k+3][sr] = vb.w;
        }
        __syncthreads();

        #pragma unroll 8
        for (int k = 0; k < TK; ++k) {
            float4 a0 = *(const float4*)&As[k][ty * 8];
            float4 a1 = *(const float4*)&As[k][ty * 8 + 4];
            float4 b0 = *(const float4*)&Bs[k][tx * 8];
            float4 b1 = *(const float4*)&Bs[k][tx * 8 + 4];
            float a[8] = {a0.x,a0.y,a0.z,a0.w,a1.x,a1.y,a1.z,a1.w};
            float b[8] = {b0.x,b0.y,b0.z,b0.w,b1.x,b1.y,b1.z,b1.w};
            #pragma unroll
            for (int i = 0; i < 8; ++i)
                #pragma unroll
                for (int j = 0; j < 8; ++j)
                    acc[i][j] = fmaf(a[i], b[j], acc[i][j]);
        }
        __syncthreads();
    }

    // epilogue: bias + store (float4)
    const float4 bias0 = *(const float4*)(bias + n0 + tx * 8);
    const float4 bias1 = *(const float4*)(bias + n0 + tx * 8 + 4);
    #pragma unroll
    for (int i = 0; i < 8; ++i) {
        int m = m0 + ty * 8 + i;
        if (m < M) {
            float* cp = C + (size_t)m * Nout + n0 + tx * 8;
            float4 r0 = make_float4(acc[i][0] + bias0.x, acc[i][1] + bias0.y,
                                    acc[i][2] + bias0.z, acc[i][3] + bias0.w);
            float4 r1 = make_float4(acc[i][4] + bias1.x, acc[i][5] + bias1.y,
                                    acc[i][6] + bias1.z, acc[i][7] + bias1.w);
            *(float4*)cp       = r0;
            *(float4*)(cp + 4) = r1;
        }
    }
}

// ---------------- per-node fused attention ----------------
// One block (128 threads) per destination node. qkv row layout per node:
// head h: q at [h*48 .. +15], k at [h*48+16 .. +31], v at [h*48+32 .. +47].
__global__ __launch_bounds__(128) void node_attn_kernel(
    const float* __restrict__ qkv, const int* __restrict__ csr_src,
    const int* __restrict__ offsets, const int* __restrict__ counts,
    float* __restrict__ agg, int N)
{
    const int n = blockIdx.x;
    const int t = threadIdx.x;

    __shared__ int   srcs_s[16];
    __shared__ float ss[16][8];             // [edge][head]

    const int row0 = offsets[n];
    const int deg  = counts[n];

    // phase-A mapping: (edge eA, head hA); preload q for this head
    const int hA = t & 7, eA = t >> 3;
    const float4* qp = (const float4*)(qkv + (size_t)n * NQKV + hA * 48);
    const float4 q0 = qp[0], q1 = qp[1], q2 = qp[2], q3 = qp[3];

    // phase-B mapping: (head hB, dim d)
    const int hB = t >> 4, d = t & 15;

    float m_run = -__builtin_inff();
    float l_run = 0.f;
    float acc   = 0.f;

    for (int c = 0; c < deg; c += 16) {
        __syncthreads();                    // protect srcs_s/ss from previous iter readers
        if (t < 16 && c + t < deg) srcs_s[t] = csr_src[row0 + c + t];
        __syncthreads();

        // ---- phase A: scores ----
        float s = -__builtin_inff();
        if (c + eA < deg) {
            int sv = srcs_s[eA];
            const float4* kp = (const float4*)(qkv + (size_t)sv * NQKV + hA * 48 + 16);
            float4 k0 = kp[0], k1 = kp[1], k2 = kp[2], k3 = kp[3];
            s = k0.x*q0.x + k0.y*q0.y + k0.z*q0.z + k0.w*q0.w
              + k1.x*q1.x + k1.y*q1.y + k1.z*q1.z + k1.w*q1.w
              + k2.x*q2.x + k2.y*q2.y + k2.z*q2.z + k2.w*q2.w
              + k3.x*q3.x + k3.y*q3.y + k3.z*q3.z + k3.w*q3.w;
            s *= 0.25f;                     // 1/sqrt(16)
        }
        ss[eA][hA] = s;
        __syncthreads();

        // ---- phase B: online softmax + V aggregation ----
        int cnt = min(16, deg - c);
        float cmax = -__builtin_inff();
        for (int i = 0; i < cnt; ++i) cmax = fmaxf(cmax, ss[i][hB]);
        float m_new = fmaxf(m_run, cmax);
        float scale = __expf(m_run - m_new);    // first iter: exp(-inf)=0
        acc   *= scale;
        l_run *= scale;
        for (int i = 0; i < cnt; ++i) {
            float p = __expf(ss[i][hB] - m_new);
            l_run += p;
            int sv = srcs_s[i];
            acc += p * qkv[(size_t)sv * NQKV + hB * 48 + 32 + d];
        }
        m_run = m_new;
    }

    // deg==0: acc=0, l_run=0 -> 0 (matches reference: empty segment -> agg 0)
    agg[(size_t)n * DD + t] = acc / fmaxf(l_run, 1e-30f);
}

// ---------------- launch ----------------
extern "C" void kernel_launch(void* const* d_in, const int* in_sizes, int n_in,
                              void* d_out, int out_size, void* d_ws, size_t ws_size,
                              hipStream_t stream) {
    const float* x     = (const float*)d_in[0];
    const int*   src   = (const int*)  d_in[1];
    const int*   dst   = (const int*)  d_in[2];
    const float* w_qkv = (const float*)d_in[3];
    const float* b_qkv = (const float*)d_in[4];
    const float* w_out = (const float*)d_in[5];
    const float* b_out = (const float*)d_in[6];
    float* out = (float*)d_out;

    const int N = in_sizes[0] / DD;   // 50000
    const int E = in_sizes[1];        // 800000

    char* ws = (char*)d_ws;
    float* qkv    = (float*)ws;  ws += (size_t)N * NQKV * sizeof(float); // 76.8 MB
    int* counts   = (int*)ws;    ws += (size_t)N * sizeof(int);
    int* offsets  = (int*)ws;    ws += (size_t)N * sizeof(int);
    int* cursor   = (int*)ws;    ws += (size_t)N * sizeof(int);
    int* bsums    = (int*)ws;    ws += 256 * sizeof(int);
    int* csr_src  = (int*)ws;    ws += (size_t)E * sizeof(int);
    float* agg    = (float*)ws;  ws += (size_t)N * DD * sizeof(float);   // 25.6 MB

    const int nb  = (N + 255) / 256;   // 196 (<=256 so single-block scan of bsums works)
    const int neb = (E + 255) / 256;

    // CSR build (by dst)
    zero_i32_kernel <<<nb, 256, 0, stream>>>(counts, N);
    hist_kernel     <<<neb, 256, 0, stream>>>(dst, counts, E);
    scan_partial_kernel<<<nb, 256, 0, stream>>>(counts, offsets, bsums, N);
    scan_sums_kernel<<<1, 256, 0, stream>>>(bsums, nb);
    scan_add_kernel <<<nb, 256, 0, stream>>>(offsets, bsums, cursor, N);
    scatter_kernel  <<<neb, 256, 0, stream>>>(src, dst, cursor, csr_src, E);

    // QKV projection: qkv = x @ w_qkv^T + b_qkv   (Nout=384 -> 3 col-tiles)
    sgemm_kernel<<<dim3((N + TM - 1) / TM, NQKV / TN), 256, 0, stream>>>(
        x, w_qkv, b_qkv, qkv, N, NQKV);

    // fused per-node softmax-attention aggregation
    node_attn_kernel<<<N, 128, 0, stream>>>(qkv, csr_src, offsets, counts, agg, N);

    // output projection: out = agg @ w_out^T + b_out
    sgemm_kernel<<<dim3((N + TM - 1) / TM, DD / TN), 256, 0, stream>>>(
        agg, w_out, b_out, out, N, DD);
}

// Round 3
// 366.162 us; speedup vs baseline: 1.9123x; 1.2785x over previous
//
#include <hip/hip_runtime.h>
#include <math.h>

#define DD   128
#define HH   8
#define NQKV 384

// ---------------- bf16 helpers ----------------
__device__ __forceinline__ unsigned short f2bf(float f) {
    unsigned u = __float_as_uint(f);
    u += 0x7fffu + ((u >> 16) & 1u);       // RTNE
    return (unsigned short)(u >> 16);
}
__device__ __forceinline__ float bf2f(unsigned short h) {
    return __uint_as_float(((unsigned)h) << 16);
}
__device__ __forceinline__ float bflo(unsigned u) { return __uint_as_float(u << 16); }
__device__ __forceinline__ float bfhi(unsigned u) { return __uint_as_float(u & 0xffff0000u); }

// ---------------- utility kernels ----------------
__global__ void zero_i32_kernel(int* __restrict__ p, int n) {
    int i = blockIdx.x * blockDim.x + threadIdx.x;
    if (i < n) p[i] = 0;
}

__global__ void hist_kernel(const int* __restrict__ dst, int* __restrict__ counts, int E) {
    int e = blockIdx.x * blockDim.x + threadIdx.x;
    if (e < E) atomicAdd(&counts[dst[e]], 1);
}

__global__ void scan_partial_kernel(const int* __restrict__ in, int* __restrict__ out,
                                    int* __restrict__ bsums, int n) {
    __shared__ int s[256];
    int tid = threadIdx.x;
    int gid = blockIdx.x * 256 + tid;
    int v = (gid < n) ? in[gid] : 0;
    s[tid] = v;
    __syncthreads();
    for (int off = 1; off < 256; off <<= 1) {
        int t = (tid >= off) ? s[tid - off] : 0;
        __syncthreads();
        s[tid] += t;
        __syncthreads();
    }
    if (gid < n) out[gid] = s[tid] - v;      // exclusive
    if (tid == 255) bsums[blockIdx.x] = s[255];
}

__global__ void scan_sums_kernel(int* __restrict__ bs, int nb) {
    __shared__ int s[256];
    int tid = threadIdx.x;
    int v = (tid < nb) ? bs[tid] : 0;
    s[tid] = v;
    __syncthreads();
    for (int off = 1; off < 256; off <<= 1) {
        int t = (tid >= off) ? s[tid - off] : 0;
        __syncthreads();
        s[tid] += t;
        __syncthreads();
    }
    if (tid < nb) bs[tid] = s[tid] - v;      // exclusive, in place
}

__global__ void scan_add_kernel(int* __restrict__ offs, const int* __restrict__ bs,
                                int* __restrict__ cursor, int n) {
    int gid = blockIdx.x * blockDim.x + threadIdx.x;
    if (gid < n) {
        int o = offs[gid] + bs[gid >> 8];
        offs[gid]   = o;
        cursor[gid] = o;
    }
}

__global__ void scatter_kernel(const int* __restrict__ src, const int* __restrict__ dst,
                               int* __restrict__ cursor, int* __restrict__ csr_src, int E) {
    int e = blockIdx.x * blockDim.x + threadIdx.x;
    if (e < E) {
        int pos = atomicAdd(&cursor[dst[e]], 1);
        csr_src[pos] = src[e];
    }
}

// ---------------- tiled SGEMM: 128x128 tile, TK=32, 8x8 micro-tile -----------------
// SPLIT_QKV=1: Nout=384 QKV projection; epilogue scatters columns into packed
//   q[N][128] fp32, k[N][128] bf16, v[N][128] bf16 (per-head 16-col segments).
//   Each thread's 8-col chunk is 8-aligned -> never straddles a 16-col segment.
// SPLIT_QKV=0: plain C[M][Nout] fp32 output (Cq).
#define TM 128
#define TN 128
#define TK 32

template<int SPLIT_QKV>
__global__ __launch_bounds__(256, 2) void sgemm_kernel(
    const float* __restrict__ A, const float* __restrict__ B,
    const float* __restrict__ bias, float* __restrict__ Cq,
    unsigned short* __restrict__ Ck, unsigned short* __restrict__ Cv,
    int M, int Nout)
{
    __shared__ float As[TK][TM];   // 16 KB
    __shared__ float Bs[TK][TN];   // 16 KB

    const int tid = threadIdx.x;
    const int tx  = tid & 15;      // col group  (8 cols each)
    const int ty  = tid >> 4;      // row group  (8 rows each)
    const int m0  = blockIdx.x * TM;
    const int n0  = blockIdx.y * TN;

    const int sr  = tid & 127;           // staging row in tile
    const int sc0 = tid >> 7;            // 0..1

    float acc[8][8];
    #pragma unroll
    for (int i = 0; i < 8; ++i)
        #pragma unroll
        for (int j = 0; j < 8; ++j) acc[i][j] = 0.f;

    const int am = m0 + sr;
    const int bn = n0 + sr;
    const float4* Arow = (const float4*)(A + (size_t)am * DD);
    const float4* Brow = (const float4*)(B + (size_t)bn * DD);
    const bool a_ok = (am < M);
    const bool b_ok = (bn < Nout);

    for (int kc = 0; kc < DD; kc += TK) {
        const int kc4 = kc >> 2;
        #pragma unroll
        for (int i = 0; i < 4; ++i) {
            int c4 = sc0 + 2 * i;        // 0..7
            float4 va = a_ok ? Arow[kc4 + c4] : make_float4(0.f,0.f,0.f,0.f);
            float4 vb = b_ok ? Brow[kc4 + c4] : make_float4(0.f,0.f,0.f,0.f);
            int k = c4 * 4;
            As[k+0][sr] = va.x; As[k+1][sr] = va.y; As[k+2][sr] = va.z; As[k+3][sr] = va.w;
            Bs[k+0][sr] = vb.x; Bs[k+1][sr] = vb.y; Bs[k+2][sr] = vb.z; Bs[k+3][sr] = vb.w;
        }
        __syncthreads();

        #pragma unroll 8
        for (int k = 0; k < TK; ++k) {
            float4 a0 = *(const float4*)&As[k][ty * 8];
            float4 a1 = *(const float4*)&As[k][ty * 8 + 4];
            float4 b0 = *(const float4*)&Bs[k][tx * 8];
            float4 b1 = *(const float4*)&Bs[k][tx * 8 + 4];
            float a[8] = {a0.x,a0.y,a0.z,a0.w,a1.x,a1.y,a1.z,a1.w};
            float b[8] = {b0.x,b0.y,b0.z,b0.w,b1.x,b1.y,b1.z,b1.w};
            #pragma unroll
            for (int i = 0; i < 8; ++i)
                #pragma unroll
                for (int j = 0; j < 8; ++j)
                    acc[i][j] = fmaf(a[i], b[j], acc[i][j]);
        }
        __syncthreads();
    }

    const int j0 = n0 + tx * 8;          // global col of this thread's 8-col chunk
    const float4 bias0 = *(const float4*)(bias + j0);
    const float4 bias1 = *(const float4*)(bias + j0 + 4);

    if (SPLIT_QKV) {
        const int h   = j0 / 48;
        const int r   = j0 - h * 48;                     // 0,8,16,24,32,40
        const int seg = (r >= 32) ? 2 : (r >= 16 ? 1 : 0);
        const int base = h * 16 + (r - seg * 16);        // packed col, 8-aligned
        #pragma unroll
        for (int i = 0; i < 8; ++i) {
            int m = m0 + ty * 8 + i;
            if (m >= M) continue;
            float v0 = acc[i][0] + bias0.x, v1 = acc[i][1] + bias0.y;
            float v2 = acc[i][2] + bias0.z, v3 = acc[i][3] + bias0.w;
            float v4 = acc[i][4] + bias1.x, v5 = acc[i][5] + bias1.y;
            float v6 = acc[i][6] + bias1.z, v7 = acc[i][7] + bias1.w;
            if (seg == 0) {
                float* qp = Cq + (size_t)m * DD + base;
                *(float4*)qp       = make_float4(v0, v1, v2, v3);
                *(float4*)(qp + 4) = make_float4(v4, v5, v6, v7);
            } else {
                unsigned short* dstp = (seg == 1 ? Ck : Cv) + (size_t)m * DD + base;
                uint4 pk;
                pk.x = (unsigned)f2bf(v0) | ((unsigned)f2bf(v1) << 16);
                pk.y = (unsigned)f2bf(v2) | ((unsigned)f2bf(v3) << 16);
                pk.z = (unsigned)f2bf(v4) | ((unsigned)f2bf(v5) << 16);
                pk.w = (unsigned)f2bf(v6) | ((unsigned)f2bf(v7) << 16);
                *(uint4*)dstp = pk;
            }
        }
    } else {
        #pragma unroll
        for (int i = 0; i < 8; ++i) {
            int m = m0 + ty * 8 + i;
            if (m >= M) continue;
            float* cp = Cq + (size_t)m * Nout + j0;
            *(float4*)cp = make_float4(acc[i][0] + bias0.x, acc[i][1] + bias0.y,
                                       acc[i][2] + bias0.z, acc[i][3] + bias0.w);
            *(float4*)(cp + 4) = make_float4(acc[i][4] + bias1.x, acc[i][5] + bias1.y,
                                             acc[i][6] + bias1.z, acc[i][7] + bias1.w);
        }
    }
}

// ---------------- per-node fused attention (packed q fp32, k/v bf16) ----------------
// One block (128 threads) per destination node.
__global__ __launch_bounds__(128) void node_attn_kernel(
    const float* __restrict__ q, const unsigned short* __restrict__ kbf,
    const unsigned short* __restrict__ vbf, const int* __restrict__ csr_src,
    const int* __restrict__ offsets, const int* __restrict__ counts,
    float* __restrict__ agg, int N)
{
    const int n = blockIdx.x;
    const int t = threadIdx.x;

    __shared__ int   srcs_s[16];
    __shared__ float ss[16][8];             // [edge][head]

    const int row0 = offsets[n];
    const int deg  = counts[n];

    // phase-A mapping: (edge eA, head hA); preload q for this head (fp32, packed)
    const int hA = t & 7, eA = t >> 3;
    const float4* qp = (const float4*)(q + (size_t)n * DD + hA * 16);
    const float4 q0 = qp[0], q1 = qp[1], q2 = qp[2], q3 = qp[3];

    // phase-B mapping: lane t covers packed col t = hB*16+d
    const int hB = t >> 4;

    float m_run = -__builtin_inff();
    float l_run = 0.f;
    float acc   = 0.f;

    for (int c = 0; c < deg; c += 16) {
        __syncthreads();                    // protect srcs_s/ss from previous iter readers
        if (t < 16 && c + t < deg) srcs_s[t] = csr_src[row0 + c + t];
        __syncthreads();

        // ---- phase A: scores (k row = 32 contiguous bytes per head, bf16) ----
        float s = -__builtin_inff();
        if (c + eA < deg) {
            int sv = srcs_s[eA];
            const uint4* kp = (const uint4*)(kbf + (size_t)sv * DD + hA * 16);
            uint4 ka = kp[0], kb = kp[1];
            s = bflo(ka.x)*q0.x + bfhi(ka.x)*q0.y + bflo(ka.y)*q0.z + bfhi(ka.y)*q0.w
              + bflo(ka.z)*q1.x + bfhi(ka.z)*q1.y + bflo(ka.w)*q1.z + bfhi(ka.w)*q1.w
              + bflo(kb.x)*q2.x + bfhi(kb.x)*q2.y + bflo(kb.y)*q2.z + bfhi(kb.y)*q2.w
              + bflo(kb.z)*q3.x + bfhi(kb.z)*q3.y + bflo(kb.w)*q3.z + bfhi(kb.w)*q3.w;
            s *= 0.25f;                     // 1/sqrt(16)
        }
        ss[eA][hA] = s;
        __syncthreads();

        // ---- phase B: online softmax + V aggregation (coalesced bf16 reads) ----
        int cnt = min(16, deg - c);
        float cmax = -__builtin_inff();
        for (int i = 0; i < cnt; ++i) cmax = fmaxf(cmax, ss[i][hB]);
        float m_new = fmaxf(m_run, cmax);
        float scale = __expf(m_run - m_new);    // first iter: exp(-inf)=0
        acc   *= scale;
        l_run *= scale;
        int i = 0;
        for (; i + 1 < cnt; i += 2) {           // 2-wide for memory-level parallelism
            int s0 = srcs_s[i], s1 = srcs_s[i + 1];
            float p0 = __expf(ss[i][hB] - m_new);
            float p1 = __expf(ss[i + 1][hB] - m_new);
            float vv0 = bf2f(vbf[(size_t)s0 * DD + t]);
            float vv1 = bf2f(vbf[(size_t)s1 * DD + t]);
            l_run += p0 + p1;
            acc = fmaf(p0, vv0, acc);
            acc = fmaf(p1, vv1, acc);
        }
        if (i < cnt) {
            int s0 = srcs_s[i];
            float p0 = __expf(ss[i][hB] - m_new);
            float vv0 = bf2f(vbf[(size_t)s0 * DD + t]);
            l_run += p0;
            acc = fmaf(p0, vv0, acc);
        }
        m_run = m_new;
    }

    // deg==0: acc=0, l_run=0 -> 0 (matches reference: empty segment -> agg 0)
    agg[(size_t)n * DD + t] = acc / fmaxf(l_run, 1e-30f);
}

// ---------------- launch ----------------
extern "C" void kernel_launch(void* const* d_in, const int* in_sizes, int n_in,
                              void* d_out, int out_size, void* d_ws, size_t ws_size,
                              hipStream_t stream) {
    const float* x     = (const float*)d_in[0];
    const int*   src   = (const int*)  d_in[1];
    const int*   dst   = (const int*)  d_in[2];
    const float* w_qkv = (const float*)d_in[3];
    const float* b_qkv = (const float*)d_in[4];
    const float* w_out = (const float*)d_in[5];
    const float* b_out = (const float*)d_in[6];
    float* out = (float*)d_out;

    const int N = in_sizes[0] / DD;   // 50000
    const int E = in_sizes[1];        // 800000

    char* ws = (char*)d_ws;
    float* qf           = (float*)ws;          ws += (size_t)N * DD * sizeof(float);  // 25.6 MB
    unsigned short* kbf = (unsigned short*)ws; ws += (size_t)N * DD * sizeof(short);  // 12.8 MB
    unsigned short* vbf = (unsigned short*)ws; ws += (size_t)N * DD * sizeof(short);  // 12.8 MB
    int* counts   = (int*)ws;    ws += (size_t)N * sizeof(int);
    int* offsets  = (int*)ws;    ws += (size_t)N * sizeof(int);
    int* cursor   = (int*)ws;    ws += (size_t)N * sizeof(int);
    int* bsums    = (int*)ws;    ws += 256 * sizeof(int);
    int* csr_src  = (int*)ws;    ws += (size_t)E * sizeof(int);
    float* agg    = (float*)ws;  ws += (size_t)N * DD * sizeof(float);                // 25.6 MB

    const int nb  = (N + 255) / 256;   // 196 (<=256 so single-block scan of bsums works)
    const int neb = (E + 255) / 256;

    // CSR build (by dst)
    zero_i32_kernel <<<nb, 256, 0, stream>>>(counts, N);
    hist_kernel     <<<neb, 256, 0, stream>>>(dst, counts, E);
    scan_partial_kernel<<<nb, 256, 0, stream>>>(counts, offsets, bsums, N);
    scan_sums_kernel<<<1, 256, 0, stream>>>(bsums, nb);
    scan_add_kernel <<<nb, 256, 0, stream>>>(offsets, bsums, cursor, N);
    scatter_kernel  <<<neb, 256, 0, stream>>>(src, dst, cursor, csr_src, E);

    // QKV projection with split epilogue: q fp32, k/v bf16, packed [N][128]
    sgemm_kernel<1><<<dim3((N + TM - 1) / TM, NQKV / TN), 256, 0, stream>>>(
        x, w_qkv, b_qkv, qf, kbf, vbf, N, NQKV);

    // fused per-node softmax-attention aggregation
    node_attn_kernel<<<N, 128, 0, stream>>>(qf, kbf, vbf, csr_src, offsets, counts, agg, N);

    // output projection: out = agg @ w_out^T + b_out
    sgemm_kernel<0><<<dim3((N + TM - 1) / TM, DD / TN), 256, 0, stream>>>(
        agg, w_out, b_out, out, nullptr, nullptr, N, DD);
}

// Round 4
// 329.446 us; speedup vs baseline: 2.1255x; 1.1114x over previous
//
#include <hip/hip_runtime.h>
#include <math.h>

#define DD   128
#define NQKV 384

typedef __attribute__((ext_vector_type(8))) short          bf16x8;
typedef __attribute__((ext_vector_type(8))) unsigned short ushort8;
typedef __attribute__((ext_vector_type(4))) float          f32x4;

// ---------------- bf16 helpers ----------------
__device__ __forceinline__ unsigned short f2bf(float f) {
    unsigned u = __float_as_uint(f);
    u += 0x7fffu + ((u >> 16) & 1u);       // RTNE
    return (unsigned short)(u >> 16);
}
__device__ __forceinline__ float bf2f(unsigned short h) {
    return __uint_as_float(((unsigned)h) << 16);
}

// ---------------- utility kernels ----------------
__global__ void zero_i32_kernel(int* __restrict__ p, int n) {
    int i = blockIdx.x * blockDim.x + threadIdx.x;
    if (i < n) p[i] = 0;
}

__global__ void hist_kernel(const int* __restrict__ dst, int* __restrict__ counts, int E) {
    int e = blockIdx.x * blockDim.x + threadIdx.x;
    if (e < E) atomicAdd(&counts[dst[e]], 1);
}

__global__ void scan_partial_kernel(const int* __restrict__ in, int* __restrict__ out,
                                    int* __restrict__ bsums, int n) {
    __shared__ int s[256];
    int tid = threadIdx.x;
    int gid = blockIdx.x * 256 + tid;
    int v = (gid < n) ? in[gid] : 0;
    s[tid] = v;
    __syncthreads();
    for (int off = 1; off < 256; off <<= 1) {
        int t = (tid >= off) ? s[tid - off] : 0;
        __syncthreads();
        s[tid] += t;
        __syncthreads();
    }
    if (gid < n) out[gid] = s[tid] - v;      // exclusive
    if (tid == 255) bsums[blockIdx.x] = s[255];
}

__global__ void scan_sums_kernel(int* __restrict__ bs, int nb) {
    __shared__ int s[256];
    int tid = threadIdx.x;
    int v = (tid < nb) ? bs[tid] : 0;
    s[tid] = v;
    __syncthreads();
    for (int off = 1; off < 256; off <<= 1) {
        int t = (tid >= off) ? s[tid - off] : 0;
        __syncthreads();
        s[tid] += t;
        __syncthreads();
    }
    if (tid < nb) bs[tid] = s[tid] - v;      // exclusive, in place
}

__global__ void scan_add_kernel(int* __restrict__ offs, const int* __restrict__ bs,
                                int* __restrict__ cursor, int n) {
    int gid = blockIdx.x * blockDim.x + threadIdx.x;
    if (gid < n) {
        int o = offs[gid] + bs[gid >> 8];
        offs[gid]   = o;
        cursor[gid] = o;
    }
}

__global__ void scatter_kernel(const int* __restrict__ src, const int* __restrict__ dst,
                               int* __restrict__ cursor, int* __restrict__ csr_src, int E) {
    int e = blockIdx.x * blockDim.x + threadIdx.x;
    if (e < E) {
        int pos = atomicAdd(&cursor[dst[e]], 1);
        csr_src[pos] = src[e];
    }
}

// ---------------- fp32 -> (bf16 hi, bf16 lo) split ----------------
// hi = bf16(x); lo = bf16(x - hi). x - hi is exact in fp32 (two-term split).
__global__ void split_kernel(const float* __restrict__ in, unsigned short* __restrict__ hi,
                             unsigned short* __restrict__ lo, int n8) {
    int i = blockIdx.x * blockDim.x + threadIdx.x;
    if (i >= n8) return;
    const float4* p = (const float4*)in + (size_t)i * 2;
    float4 a = p[0], b = p[1];
    float v[8] = {a.x, a.y, a.z, a.w, b.x, b.y, b.z, b.w};
    ushort8 vh, vl;
    #pragma unroll
    for (int j = 0; j < 8; ++j) {
        unsigned short h = f2bf(v[j]);
        vh[j] = h;
        vl[j] = f2bf(v[j] - bf2f(h));
    }
    *(ushort8*)(hi + (size_t)i * 8) = vh;
    *(ushort8*)(lo + (size_t)i * 8) = vl;
}

// ---------------- split-bf16 MFMA GEMM: C[M][Nout] = A[M][128] @ B[Nout][128]^T + bias
// A,B given as bf16 hi/lo pairs; acc = Ah*Bh + Ah*Bl + Al*Bh (fp32-accurate).
// 256 thr = 4 waves (2x2 of 64x64), tile 128x128, BK=32, mfma_f32_16x16x32_bf16.
// SPLIT_QKV=1: scatter cols into packed q[N][128] fp32, k/v[N][128] bf16.
#define TM 128
#define TN 128
#define LDA 40   // padded LDS row stride in shorts (80 B -> 2-way bank aliasing, free)

template<int SPLIT_QKV>
__global__ __launch_bounds__(256, 2) void mfma_gemm_kernel(
    const unsigned short* __restrict__ Ah, const unsigned short* __restrict__ Al,
    const unsigned short* __restrict__ Bh, const unsigned short* __restrict__ Bl,
    const float* __restrict__ bias, float* __restrict__ Cq,
    unsigned short* __restrict__ Ck, unsigned short* __restrict__ Cv,
    int M, int Nout)
{
    __shared__ unsigned short As_h[TM * LDA];   // 10240 B each, 40 KB total
    __shared__ unsigned short As_l[TM * LDA];
    __shared__ unsigned short Bs_h[TN * LDA];
    __shared__ unsigned short Bs_l[TN * LDA];

    const int tid  = threadIdx.x;
    const int l    = tid & 63;
    const int wv   = tid >> 6;
    const int quad = l >> 4;
    const int l15  = l & 15;
    const int wm   = (wv & 1) * 64;
    const int wn   = (wv >> 1) * 64;
    const int m0   = blockIdx.x * TM;
    const int n0   = blockIdx.y * TN;

    f32x4 acc[4][4];
    #pragma unroll
    for (int i = 0; i < 4; ++i)
        #pragma unroll
        for (int j = 0; j < 4; ++j) acc[i][j] = (f32x4)0.f;

    #pragma unroll
    for (int kc = 0; kc < DD; kc += 32) {
        // ---- stage A/B chunk (rows x 32 k-cols, hi+lo) ----
        #pragma unroll
        for (int it = 0; it < 2; ++it) {
            int idx = tid + it * 256;       // 0..511
            int row = idx >> 2;             // 0..127
            int pc  = idx & 3;              // 16B piece within 64B row-chunk
            int loff = row * LDA + pc * 8;
            size_t ga = (size_t)(m0 + row) * DD + kc + pc * 8;
            ushort8 vh = 0, vl = 0;
            if (m0 + row < M) {
                vh = *(const ushort8*)(Ah + ga);
                vl = *(const ushort8*)(Al + ga);
            }
            *(ushort8*)&As_h[loff] = vh;
            *(ushort8*)&As_l[loff] = vl;
            size_t gb = (size_t)(n0 + row) * DD + kc + pc * 8;   // Nout % 128 == 0
            *(ushort8*)&Bs_h[loff] = *(const ushort8*)(Bh + gb);
            *(ushort8*)&Bs_l[loff] = *(const ushort8*)(Bl + gb);
        }
        __syncthreads();

        // ---- fragments: A[m=l15][k=quad*8+j] / B[n=l15][k=quad*8+j] ----
        bf16x8 ah[4], al[4], bh[4], bl[4];
        #pragma unroll
        for (int mt = 0; mt < 4; ++mt) {
            int off = (wm + mt * 16 + l15) * LDA + quad * 8;
            ah[mt] = *(const bf16x8*)&As_h[off];
            al[mt] = *(const bf16x8*)&As_l[off];
        }
        #pragma unroll
        for (int nt = 0; nt < 4; ++nt) {
            int off = (wn + nt * 16 + l15) * LDA + quad * 8;
            bh[nt] = *(const bf16x8*)&Bs_h[off];
            bl[nt] = *(const bf16x8*)&Bs_l[off];
        }
        #pragma unroll
        for (int mt = 0; mt < 4; ++mt)
            #pragma unroll
            for (int nt = 0; nt < 4; ++nt) {
                acc[mt][nt] = __builtin_amdgcn_mfma_f32_16x16x32_bf16(ah[mt], bh[nt], acc[mt][nt], 0, 0, 0);
                acc[mt][nt] = __builtin_amdgcn_mfma_f32_16x16x32_bf16(ah[mt], bl[nt], acc[mt][nt], 0, 0, 0);
                acc[mt][nt] = __builtin_amdgcn_mfma_f32_16x16x32_bf16(al[mt], bh[nt], acc[mt][nt], 0, 0, 0);
            }
        __syncthreads();
    }

    // ---- epilogue: C/D layout col=l15, row=quad*4+rr ----
    #pragma unroll
    for (int nt = 0; nt < 4; ++nt) {
        int j = n0 + wn + nt * 16 + l15;
        float bj = bias[j];
        int h = 0, seg = 0, bc = 0;
        if (SPLIT_QKV) {
            h = j / 48;
            int r = j - h * 48;
            seg = (r >= 32) ? 2 : ((r >= 16) ? 1 : 0);
            bc  = h * 16 + r - seg * 16;
        }
        #pragma unroll
        for (int mt = 0; mt < 4; ++mt) {
            #pragma unroll
            for (int rr = 0; rr < 4; ++rr) {
                int m = m0 + wm + mt * 16 + quad * 4 + rr;
                if (m >= M) continue;
                float val = acc[mt][nt][rr] + bj;
                if (SPLIT_QKV) {
                    if (seg == 0)      Cq[(size_t)m * DD + bc] = val;
                    else if (seg == 1) Ck[(size_t)m * DD + bc] = f2bf(val);
                    else               Cv[(size_t)m * DD + bc] = f2bf(val);
                } else {
                    Cq[(size_t)m * Nout + j] = val;
                }
            }
        }
    }
}

// ---------------- per-node fused attention (packed q fp32, k/v bf16) ----------------
// One block (128 threads) per destination node; probs computed once per (edge,head).
__global__ __launch_bounds__(128) void node_attn_kernel(
    const float* __restrict__ q, const unsigned short* __restrict__ kbf,
    const unsigned short* __restrict__ vbf, const int* __restrict__ csr_src,
    const int* __restrict__ offsets, const int* __restrict__ counts,
    unsigned short* __restrict__ agg_hi, unsigned short* __restrict__ agg_lo, int N)
{
    const int n = blockIdx.x;
    const int t = threadIdx.x;

    __shared__ int   srcs_s[16];
    __shared__ float ss[16][8];             // scores  [edge][head]
    __shared__ float ps[16][8];             // probs   [edge][head]
    __shared__ float mh[8], sc[8];          // per-head m_new, rescale

    const int row0 = offsets[n];
    const int deg  = counts[n];

    // phase-A mapping: (edge eA, head hA); preload q for this head (fp32, packed)
    const int hA = t & 7, eA = t >> 3;
    const float4* qp = (const float4*)(q + (size_t)n * DD + hA * 16);
    const float4 q0 = qp[0], q1 = qp[1], q2 = qp[2], q3 = qp[3];

    // phase-B mapping: lane t covers packed col t = hB*16 + d
    const int hB = t >> 4;

    float mrun_h = -__builtin_inff();       // per-head running max (valid for t<8, head=t)
    float l_run = 0.f;
    float acc   = 0.f;

    for (int c = 0; c < deg; c += 16) {
        __syncthreads();                    // protect LDS from previous-iter readers
        if (t < 16 && c + t < deg) srcs_s[t] = csr_src[row0 + c + t];
        __syncthreads();

        // ---- phase A: scores ----
        float s = -__builtin_inff();
        if (c + eA < deg) {
            int sv = srcs_s[eA];
            const uint4* kp = (const uint4*)(kbf + (size_t)sv * DD + hA * 16);
            uint4 ka = kp[0], kb = kp[1];
            #define BLO(u) __uint_as_float((u) << 16)
            #define BHI(u) __uint_as_float((u) & 0xffff0000u)
            s = BLO(ka.x)*q0.x + BHI(ka.x)*q0.y + BLO(ka.y)*q0.z + BHI(ka.y)*q0.w
              + BLO(ka.z)*q1.x + BHI(ka.z)*q1.y + BLO(ka.w)*q1.z + BHI(ka.w)*q1.w
              + BLO(kb.x)*q2.x + BHI(kb.x)*q2.y + BLO(kb.y)*q2.z + BHI(kb.y)*q2.w
              + BLO(kb.z)*q3.x + BHI(kb.z)*q3.y + BLO(kb.w)*q3.z + BHI(kb.w)*q3.w;
            s *= 0.25f;                     // 1/sqrt(16)
            #undef BLO
            #undef BHI
        }
        ss[eA][hA] = s;
        __syncthreads();

        const int cnt = min(16, deg - c);

        // ---- per-head max + rescale (8 scan lanes) ----
        if (t < 8) {
            float cmax = -__builtin_inff();
            for (int i = 0; i < cnt; ++i) cmax = fmaxf(cmax, ss[i][t]);
            float m_new = fmaxf(mrun_h, cmax);      // finite: cnt>=1, scores finite
            sc[t] = __expf(mrun_h - m_new);         // first chunk: exp(-inf)=0
            mh[t] = m_new;
            mrun_h = m_new;
        }
        __syncthreads();

        // ---- probs: one exp per (edge,head) ----
        float p = (eA < cnt) ? __expf(ss[eA][hA] - mh[hA]) : 0.f;
        ps[eA][hA] = p;
        __syncthreads();

        // ---- phase B: rescale + fma aggregation (coalesced bf16 v reads) ----
        float scale = sc[hB];
        acc   *= scale;
        l_run *= scale;
        int i = 0;
        for (; i + 1 < cnt; i += 2) {
            int s0 = srcs_s[i], s1 = srcs_s[i + 1];
            float p0 = ps[i][hB], p1 = ps[i + 1][hB];
            float v0 = bf2f(vbf[(size_t)s0 * DD + t]);
            float v1 = bf2f(vbf[(size_t)s1 * DD + t]);
            l_run += p0 + p1;
            acc = fmaf(p0, v0, acc);
            acc = fmaf(p1, v1, acc);
        }
        if (i < cnt) {
            int s0 = srcs_s[i];
            float p0 = ps[i][hB];
            float v0 = bf2f(vbf[(size_t)s0 * DD + t]);
            l_run += p0;
            acc = fmaf(p0, v0, acc);
        }
    }

    // deg==0: acc=0, l_run=0 -> 0 (matches reference)
    float o = acc / fmaxf(l_run, 1e-30f);
    unsigned short oh = f2bf(o);
    agg_hi[(size_t)n * DD + t] = oh;
    agg_lo[(size_t)n * DD + t] = f2bf(o - bf2f(oh));
}

// ---------------- launch ----------------
extern "C" void kernel_launch(void* const* d_in, const int* in_sizes, int n_in,
                              void* d_out, int out_size, void* d_ws, size_t ws_size,
                              hipStream_t stream) {
    const float* x     = (const float*)d_in[0];
    const int*   src   = (const int*)  d_in[1];
    const int*   dst   = (const int*)  d_in[2];
    const float* w_qkv = (const float*)d_in[3];
    const float* b_qkv = (const float*)d_in[4];
    const float* w_out = (const float*)d_in[5];
    const float* b_out = (const float*)d_in[6];
    float* out = (float*)d_out;

    const int N = in_sizes[0] / DD;   // 50000
    const int E = in_sizes[1];        // 800000

    typedef unsigned short u16;
    char* ws = (char*)d_ws;
    float* qf   = (float*)ws; ws += (size_t)N * DD * sizeof(float);   // 25.6 MB
    u16* kbf    = (u16*)ws;   ws += (size_t)N * DD * sizeof(u16);     // 12.8 MB
    u16* vbf    = (u16*)ws;   ws += (size_t)N * DD * sizeof(u16);
    u16* x_hi   = (u16*)ws;   ws += (size_t)N * DD * sizeof(u16);
    u16* x_lo   = (u16*)ws;   ws += (size_t)N * DD * sizeof(u16);
    u16* agg_hi = (u16*)ws;   ws += (size_t)N * DD * sizeof(u16);
    u16* agg_lo = (u16*)ws;   ws += (size_t)N * DD * sizeof(u16);
    u16* wq_hi  = (u16*)ws;   ws += (size_t)NQKV * DD * sizeof(u16);
    u16* wq_lo  = (u16*)ws;   ws += (size_t)NQKV * DD * sizeof(u16);
    u16* wo_hi  = (u16*)ws;   ws += (size_t)DD * DD * sizeof(u16);
    u16* wo_lo  = (u16*)ws;   ws += (size_t)DD * DD * sizeof(u16);
    int* counts  = (int*)ws;  ws += (size_t)N * sizeof(int);
    int* offsets = (int*)ws;  ws += (size_t)N * sizeof(int);
    int* cursor  = (int*)ws;  ws += (size_t)N * sizeof(int);
    int* bsums   = (int*)ws;  ws += 256 * sizeof(int);
    int* csr_src = (int*)ws;  ws += (size_t)E * sizeof(int);

    const int nb  = (N + 255) / 256;   // <=256 so single-block scan of bsums works
    const int neb = (E + 255) / 256;

    // CSR build (by dst)
    zero_i32_kernel <<<nb, 256, 0, stream>>>(counts, N);
    hist_kernel     <<<neb, 256, 0, stream>>>(dst, counts, E);
    scan_partial_kernel<<<nb, 256, 0, stream>>>(counts, offsets, bsums, N);
    scan_sums_kernel<<<1, 256, 0, stream>>>(bsums, nb);
    scan_add_kernel <<<nb, 256, 0, stream>>>(offsets, bsums, cursor, N);
    scatter_kernel  <<<neb, 256, 0, stream>>>(src, dst, cursor, csr_src, E);

    // fp32 -> bf16 hi/lo splits
    const int nx8 = N * DD / 8;
    split_kernel<<<(nx8 + 255) / 256, 256, 0, stream>>>(x, x_hi, x_lo, nx8);
    const int nwq8 = NQKV * DD / 8;
    split_kernel<<<(nwq8 + 255) / 256, 256, 0, stream>>>(w_qkv, wq_hi, wq_lo, nwq8);
    const int nwo8 = DD * DD / 8;
    split_kernel<<<(nwo8 + 255) / 256, 256, 0, stream>>>(w_out, wo_hi, wo_lo, nwo8);

    // QKV projection (split epilogue: q fp32, k/v bf16, packed [N][128])
    mfma_gemm_kernel<1><<<dim3((N + TM - 1) / TM, NQKV / TN), 256, 0, stream>>>(
        x_hi, x_lo, wq_hi, wq_lo, b_qkv, qf, kbf, vbf, N, NQKV);

    // fused per-node softmax-attention aggregation (emits agg as bf16 hi/lo)
    node_attn_kernel<<<N, 128, 0, stream>>>(qf, kbf, vbf, csr_src, offsets, counts,
                                            agg_hi, agg_lo, N);

    // output projection: out = agg @ w_out^T + b_out
    mfma_gemm_kernel<0><<<dim3((N + TM - 1) / TM, DD / TN), 256, 0, stream>>>(
        agg_hi, agg_lo, wo_hi, wo_lo, b_out, out, nullptr, nullptr, N, DD);
}

// Round 5
// 326.726 us; speedup vs baseline: 2.1432x; 1.0083x over previous
//
#include <hip/hip_runtime.h>
#include <math.h>

#define DD   128
#define NQKV 384

typedef __attribute__((ext_vector_type(8))) short          bf16x8;
typedef __attribute__((ext_vector_type(8))) unsigned short ushort8;
typedef __attribute__((ext_vector_type(4))) float          f32x4;

// ---------------- bf16 helpers ----------------
__device__ __forceinline__ unsigned short f2bf(float f) {
    unsigned u = __float_as_uint(f);
    u += 0x7fffu + ((u >> 16) & 1u);       // RTNE
    return (unsigned short)(u >> 16);
}
__device__ __forceinline__ float bf2f(unsigned short h) {
    return __uint_as_float(((unsigned)h) << 16);
}
__device__ __forceinline__ float bflo(unsigned u) { return __uint_as_float(u << 16); }
__device__ __forceinline__ float bfhi(unsigned u) { return __uint_as_float(u & 0xffff0000u); }

// ---------------- prep: zero counts + split both weight matrices ----------------
// item i < N: zero counts[i]; else weight-split item (8 elems each).
#define NWQ8 (NQKV * DD / 8)   // 6144
#define NWO8 (DD * DD / 8)     // 2048

__global__ void prep_kernel(const float* __restrict__ w_qkv, const float* __restrict__ w_out,
                            unsigned short* __restrict__ wq_hi, unsigned short* __restrict__ wq_lo,
                            unsigned short* __restrict__ wo_hi, unsigned short* __restrict__ wo_lo,
                            int* __restrict__ counts, int N) {
    int i = blockIdx.x * blockDim.x + threadIdx.x;
    if (i < N) { counts[i] = 0; return; }
    int j = i - N;
    const float* srcp;
    unsigned short *hip_, *lop_;
    if (j < NWQ8)            { srcp = w_qkv + (size_t)j * 8;          hip_ = wq_hi + (size_t)j * 8;          lop_ = wq_lo + (size_t)j * 8; }
    else if (j < NWQ8+NWO8)  { int k = j - NWQ8; srcp = w_out + (size_t)k * 8; hip_ = wo_hi + (size_t)k * 8; lop_ = wo_lo + (size_t)k * 8; }
    else return;
    const float4* p = (const float4*)srcp;
    float4 a = p[0], b = p[1];
    float v[8] = {a.x, a.y, a.z, a.w, b.x, b.y, b.z, b.w};
    ushort8 vh, vl;
    #pragma unroll
    for (int t = 0; t < 8; ++t) {
        unsigned short h = f2bf(v[t]);
        vh[t] = h;
        vl[t] = f2bf(v[t] - bf2f(h));
    }
    *(ushort8*)hip_ = vh;
    *(ushort8*)lop_ = vl;
}

// ---------------- CSR build kernels ----------------
__global__ void hist_kernel(const int* __restrict__ dst, int* __restrict__ counts, int E) {
    int e = blockIdx.x * blockDim.x + threadIdx.x;
    if (e < E) atomicAdd(&counts[dst[e]], 1);
}

__global__ void scan_partial_kernel(const int* __restrict__ in, int* __restrict__ out,
                                    int* __restrict__ bsums, int n) {
    __shared__ int s[256];
    int tid = threadIdx.x;
    int gid = blockIdx.x * 256 + tid;
    int v = (gid < n) ? in[gid] : 0;
    s[tid] = v;
    __syncthreads();
    for (int off = 1; off < 256; off <<= 1) {
        int t = (tid >= off) ? s[tid - off] : 0;
        __syncthreads();
        s[tid] += t;
        __syncthreads();
    }
    if (gid < n) out[gid] = s[tid] - v;      // exclusive
    if (tid == 255) bsums[blockIdx.x] = s[255];
}

__global__ void scan_sums_kernel(int* __restrict__ bs, int nb) {
    __shared__ int s[256];
    int tid = threadIdx.x;
    int v = (tid < nb) ? bs[tid] : 0;
    s[tid] = v;
    __syncthreads();
    for (int off = 1; off < 256; off <<= 1) {
        int t = (tid >= off) ? s[tid - off] : 0;
        __syncthreads();
        s[tid] += t;
        __syncthreads();
    }
    if (tid < nb) bs[tid] = s[tid] - v;      // exclusive, in place
}

__global__ void scan_add_kernel(int* __restrict__ offs, const int* __restrict__ bs,
                                int* __restrict__ cursor, int n) {
    int gid = blockIdx.x * blockDim.x + threadIdx.x;
    if (gid < n) {
        int o = offs[gid] + bs[gid >> 8];
        offs[gid]   = o;
        cursor[gid] = o;
    }
}

__global__ void scatter_kernel(const int* __restrict__ src, const int* __restrict__ dst,
                               int* __restrict__ cursor, int* __restrict__ csr_src, int E) {
    int e = blockIdx.x * blockDim.x + threadIdx.x;
    if (e < E) {
        int pos = atomicAdd(&cursor[dst[e]], 1);
        csr_src[pos] = src[e];
    }
}

// ---------------- MFMA GEMM tiles ----------------
#define TM 128
#define TN 128
#define LDA 40   // padded LDS row stride in shorts (80 B -> 2-way bank aliasing, free)

// QKV projection (2-pass): qkv = bf16(x) @ (w_hi + w_lo)^T + bias.
// Epilogue scatters cols into packed q[N][128] fp32, k/v[N][128] bf16.
__global__ __launch_bounds__(256, 2) void qkv_gemm_kernel(
    const float* __restrict__ X,
    const unsigned short* __restrict__ Bh, const unsigned short* __restrict__ Bl,
    const float* __restrict__ bias, float* __restrict__ Cq,
    unsigned short* __restrict__ Ck, unsigned short* __restrict__ Cv, int M)
{
    __shared__ unsigned short As[TM * LDA];     // 30 KB total
    __shared__ unsigned short Bs_h[TN * LDA];
    __shared__ unsigned short Bs_l[TN * LDA];

    const int tid  = threadIdx.x;
    const int l    = tid & 63;
    const int wv   = tid >> 6;
    const int quad = l >> 4;
    const int l15  = l & 15;
    const int wm   = (wv & 1) * 64;
    const int wn   = (wv >> 1) * 64;
    const int m0   = blockIdx.x * TM;
    const int n0   = blockIdx.y * TN;

    f32x4 acc[4][4];
    #pragma unroll
    for (int i = 0; i < 4; ++i)
        #pragma unroll
        for (int j = 0; j < 4; ++j) acc[i][j] = (f32x4)0.f;

    #pragma unroll
    for (int kc = 0; kc < DD; kc += 32) {
        #pragma unroll
        for (int it = 0; it < 2; ++it) {
            int idx = tid + it * 256;       // 0..511
            int row = idx >> 2;             // 0..127
            int pc  = idx & 3;              // 8-elem piece within 32-col chunk
            int loff = row * LDA + pc * 8;
            // A: fp32 x -> bf16 inline
            ushort8 va = 0;
            if (m0 + row < M) {
                const float4* xp = (const float4*)(X + (size_t)(m0 + row) * DD + kc + pc * 8);
                float4 a0 = xp[0], a1 = xp[1];
                float v[8] = {a0.x,a0.y,a0.z,a0.w,a1.x,a1.y,a1.z,a1.w};
                #pragma unroll
                for (int t = 0; t < 8; ++t) va[t] = f2bf(v[t]);
            }
            *(ushort8*)&As[loff] = va;
            size_t gb = (size_t)(n0 + row) * DD + kc + pc * 8;
            *(ushort8*)&Bs_h[loff] = *(const ushort8*)(Bh + gb);
            *(ushort8*)&Bs_l[loff] = *(const ushort8*)(Bl + gb);
        }
        __syncthreads();

        bf16x8 ah[4], bh[4], bl[4];
        #pragma unroll
        for (int mt = 0; mt < 4; ++mt)
            ah[mt] = *(const bf16x8*)&As[(wm + mt * 16 + l15) * LDA + quad * 8];
        #pragma unroll
        for (int nt = 0; nt < 4; ++nt) {
            int off = (wn + nt * 16 + l15) * LDA + quad * 8;
            bh[nt] = *(const bf16x8*)&Bs_h[off];
            bl[nt] = *(const bf16x8*)&Bs_l[off];
        }
        #pragma unroll
        for (int mt = 0; mt < 4; ++mt)
            #pragma unroll
            for (int nt = 0; nt < 4; ++nt) {
                acc[mt][nt] = __builtin_amdgcn_mfma_f32_16x16x32_bf16(ah[mt], bh[nt], acc[mt][nt], 0, 0, 0);
                acc[mt][nt] = __builtin_amdgcn_mfma_f32_16x16x32_bf16(ah[mt], bl[nt], acc[mt][nt], 0, 0, 0);
            }
        __syncthreads();
    }

    // epilogue: C/D layout col=l15, row=quad*4+rr; scatter into packed q/k/v
    #pragma unroll
    for (int nt = 0; nt < 4; ++nt) {
        int j = n0 + wn + nt * 16 + l15;
        float bj = bias[j];
        int h = j / 48;
        int r = j - h * 48;
        int seg = (r >= 32) ? 2 : ((r >= 16) ? 1 : 0);
        int bc  = h * 16 + r - seg * 16;
        #pragma unroll
        for (int mt = 0; mt < 4; ++mt)
            #pragma unroll
            for (int rr = 0; rr < 4; ++rr) {
                int m = m0 + wm + mt * 16 + quad * 4 + rr;
                if (m >= M) continue;
                float val = acc[mt][nt][rr] + bj;
                if (seg == 0)      Cq[(size_t)m * DD + bc] = val;
                else if (seg == 1) Ck[(size_t)m * DD + bc] = f2bf(val);
                else               Cv[(size_t)m * DD + bc] = f2bf(val);
            }
    }
}

// Out projection (3-pass split-bf16, accurate): out = (Ah+Al) @ (Bh+Bl)^T + bias
__global__ __launch_bounds__(256, 2) void out_gemm_kernel(
    const unsigned short* __restrict__ Ah, const unsigned short* __restrict__ Al,
    const unsigned short* __restrict__ Bh, const unsigned short* __restrict__ Bl,
    const float* __restrict__ bias, float* __restrict__ C, int M)
{
    __shared__ unsigned short As_h[TM * LDA];
    __shared__ unsigned short As_l[TM * LDA];
    __shared__ unsigned short Bs_h[TN * LDA];
    __shared__ unsigned short Bs_l[TN * LDA];

    const int tid  = threadIdx.x;
    const int l    = tid & 63;
    const int wv   = tid >> 6;
    const int quad = l >> 4;
    const int l15  = l & 15;
    const int wm   = (wv & 1) * 64;
    const int wn   = (wv >> 1) * 64;
    const int m0   = blockIdx.x * TM;

    f32x4 acc[4][4];
    #pragma unroll
    for (int i = 0; i < 4; ++i)
        #pragma unroll
        for (int j = 0; j < 4; ++j) acc[i][j] = (f32x4)0.f;

    #pragma unroll
    for (int kc = 0; kc < DD; kc += 32) {
        #pragma unroll
        for (int it = 0; it < 2; ++it) {
            int idx = tid + it * 256;
            int row = idx >> 2;
            int pc  = idx & 3;
            int loff = row * LDA + pc * 8;
            size_t ga = (size_t)(m0 + row) * DD + kc + pc * 8;
            ushort8 vh = 0, vl = 0;
            if (m0 + row < M) {
                vh = *(const ushort8*)(Ah + ga);
                vl = *(const ushort8*)(Al + ga);
            }
            *(ushort8*)&As_h[loff] = vh;
            *(ushort8*)&As_l[loff] = vl;
            size_t gb = (size_t)row * DD + kc + pc * 8;   // Nout == 128, one col tile
            *(ushort8*)&Bs_h[loff] = *(const ushort8*)(Bh + gb);
            *(ushort8*)&Bs_l[loff] = *(const ushort8*)(Bl + gb);
        }
        __syncthreads();

        bf16x8 ah[4], al[4], bh[4], bl[4];
        #pragma unroll
        for (int mt = 0; mt < 4; ++mt) {
            int off = (wm + mt * 16 + l15) * LDA + quad * 8;
            ah[mt] = *(const bf16x8*)&As_h[off];
            al[mt] = *(const bf16x8*)&As_l[off];
        }
        #pragma unroll
        for (int nt = 0; nt < 4; ++nt) {
            int off = (wn + nt * 16 + l15) * LDA + quad * 8;
            bh[nt] = *(const bf16x8*)&Bs_h[off];
            bl[nt] = *(const bf16x8*)&Bs_l[off];
        }
        #pragma unroll
        for (int mt = 0; mt < 4; ++mt)
            #pragma unroll
            for (int nt = 0; nt < 4; ++nt) {
                acc[mt][nt] = __builtin_amdgcn_mfma_f32_16x16x32_bf16(ah[mt], bh[nt], acc[mt][nt], 0, 0, 0);
                acc[mt][nt] = __builtin_amdgcn_mfma_f32_16x16x32_bf16(ah[mt], bl[nt], acc[mt][nt], 0, 0, 0);
                acc[mt][nt] = __builtin_amdgcn_mfma_f32_16x16x32_bf16(al[mt], bh[nt], acc[mt][nt], 0, 0, 0);
            }
        __syncthreads();
    }

    #pragma unroll
    for (int nt = 0; nt < 4; ++nt) {
        int j = wn + nt * 16 + l15;
        float bj = bias[j];
        #pragma unroll
        for (int mt = 0; mt < 4; ++mt)
            #pragma unroll
            for (int rr = 0; rr < 4; ++rr) {
                int m = m0 + wm + mt * 16 + quad * 4 + rr;
                if (m < M) C[(size_t)m * DD + j] = acc[mt][nt][rr] + bj;
            }
    }
}

// ---------------- wave-per-node fused attention (barrier-free) ----------------
// One 64-lane wave per node; 4 nodes per 256-block. Phase A: head=lane>>3,
// edge=lane&7 (8 edges/chunk). Per-head softmax state via shfl_xor over lane
// bits 0..2; phase B lane covers cols {2*lane, 2*lane+1} (head lane>>3 — same
// grouping, so per-head m/l/scale are uniform where used). No LDS, no barriers.
__global__ __launch_bounds__(256) void wave_attn_kernel(
    const float* __restrict__ q, const unsigned short* __restrict__ kbf,
    const unsigned short* __restrict__ vbf, const int* __restrict__ csr_src,
    const int* __restrict__ offsets, const int* __restrict__ counts,
    unsigned short* __restrict__ agg_hi, unsigned short* __restrict__ agg_lo, int N)
{
    const int lane = threadIdx.x & 63;
    const int n = blockIdx.x * 4 + (threadIdx.x >> 6);
    if (n >= N) return;

    const int h = lane >> 3;      // head (phases A and B)
    const int e = lane & 7;       // edge slot (phase A)

    const int row0 = offsets[n];
    const int deg  = counts[n];

    const float4* qp = (const float4*)(q + (size_t)n * DD + h * 16);
    const float4 q0 = qp[0], q1 = qp[1], q2 = qp[2], q3 = qp[3];

    float m_run = -__builtin_inff();
    float l_run = 0.f;
    float acc0 = 0.f, acc1 = 0.f;

    for (int c = 0; c < deg; c += 8) {
        const int cnt = min(8, deg - c);
        const int srcA = csr_src[row0 + c + min(e, cnt - 1)];

        // ---- phase A: score for (edge e, head h) ----
        float s = -__builtin_inff();
        if (e < cnt) {
            const uint4* kp = (const uint4*)(kbf + (size_t)srcA * DD + h * 16);
            uint4 ka = kp[0], kb = kp[1];
            s = bflo(ka.x)*q0.x + bfhi(ka.x)*q0.y + bflo(ka.y)*q0.z + bfhi(ka.y)*q0.w
              + bflo(ka.z)*q1.x + bfhi(ka.z)*q1.y + bflo(ka.w)*q1.z + bfhi(ka.w)*q1.w
              + bflo(kb.x)*q2.x + bfhi(kb.x)*q2.y + bflo(kb.y)*q2.z + bfhi(kb.y)*q2.w
              + bflo(kb.z)*q3.x + bfhi(kb.z)*q3.y + bflo(kb.w)*q3.z + bfhi(kb.w)*q3.w;
            s *= 0.25f;           // 1/sqrt(16)
        }

        // ---- per-head max over edges (butterfly over lane bits 0..2) ----
        float m_c = s;
        m_c = fmaxf(m_c, __shfl_xor(m_c, 1));
        m_c = fmaxf(m_c, __shfl_xor(m_c, 2));
        m_c = fmaxf(m_c, __shfl_xor(m_c, 4));
        const float m_new = fmaxf(m_run, m_c);     // finite (cnt>=1)

        float p = (e < cnt) ? __expf(s - m_new) : 0.f;
        float l_c = p;
        l_c += __shfl_xor(l_c, 1);
        l_c += __shfl_xor(l_c, 2);
        l_c += __shfl_xor(l_c, 4);

        const float scale = __expf(m_run - m_new); // first chunk: exp(-inf)=0
        m_run = m_new;
        l_run = l_run * scale + l_c;
        acc0 *= scale;
        acc1 *= scale;

        // ---- phase B: lane covers cols 2*lane, 2*lane+1 (head lane>>3 == h) ----
        #pragma unroll
        for (int ee = 0; ee < 8; ++ee) {
            if (ee >= cnt) break;
            const int sl = h * 8 + ee;             // lane holding (edge ee, head h)
            const float pe = __shfl(p, sl);
            const int   sv = __shfl(srcA, sl);
            const unsigned vv = *(const unsigned*)(vbf + (size_t)sv * DD + 2 * lane);
            acc0 = fmaf(pe, bflo(vv), acc0);
            acc1 = fmaf(pe, bfhi(vv), acc1);
        }
    }

    // deg==0: acc=0, l_run=0 -> 0 (matches reference)
    const float inv = 1.f / fmaxf(l_run, 1e-30f);
    const float o0 = acc0 * inv, o1 = acc1 * inv;
    const unsigned short h0 = f2bf(o0), h1 = f2bf(o1);
    const size_t base = (size_t)n * DD + 2 * lane;
    *(unsigned*)(agg_hi + base) = (unsigned)h0 | ((unsigned)h1 << 16);
    *(unsigned*)(agg_lo + base) = (unsigned)f2bf(o0 - bf2f(h0)) |
                                  ((unsigned)f2bf(o1 - bf2f(h1)) << 16);
}

// ---------------- launch ----------------
extern "C" void kernel_launch(void* const* d_in, const int* in_sizes, int n_in,
                              void* d_out, int out_size, void* d_ws, size_t ws_size,
                              hipStream_t stream) {
    const float* x     = (const float*)d_in[0];
    const int*   src   = (const int*)  d_in[1];
    const int*   dst   = (const int*)  d_in[2];
    const float* w_qkv = (const float*)d_in[3];
    const float* b_qkv = (const float*)d_in[4];
    const float* w_out = (const float*)d_in[5];
    const float* b_out = (const float*)d_in[6];
    float* out = (float*)d_out;

    const int N = in_sizes[0] / DD;   // 50000
    const int E = in_sizes[1];        // 800000

    typedef unsigned short u16;
    char* ws = (char*)d_ws;
    float* qf   = (float*)ws; ws += (size_t)N * DD * sizeof(float);   // 25.6 MB
    u16* kbf    = (u16*)ws;   ws += (size_t)N * DD * sizeof(u16);     // 12.8 MB
    u16* vbf    = (u16*)ws;   ws += (size_t)N * DD * sizeof(u16);
    u16* agg_hi = (u16*)ws;   ws += (size_t)N * DD * sizeof(u16);
    u16* agg_lo = (u16*)ws;   ws += (size_t)N * DD * sizeof(u16);
    u16* wq_hi  = (u16*)ws;   ws += (size_t)NQKV * DD * sizeof(u16);
    u16* wq_lo  = (u16*)ws;   ws += (size_t)NQKV * DD * sizeof(u16);
    u16* wo_hi  = (u16*)ws;   ws += (size_t)DD * DD * sizeof(u16);
    u16* wo_lo  = (u16*)ws;   ws += (size_t)DD * DD * sizeof(u16);
    int* counts  = (int*)ws;  ws += (size_t)N * sizeof(int);
    int* offsets = (int*)ws;  ws += (size_t)N * sizeof(int);
    int* cursor  = (int*)ws;  ws += (size_t)N * sizeof(int);
    int* bsums   = (int*)ws;  ws += 256 * sizeof(int);
    int* csr_src = (int*)ws;  ws += (size_t)E * sizeof(int);

    const int nb  = (N + 255) / 256;   // <=256 so single-block scan of bsums works
    const int neb = (E + 255) / 256;
    const int npb = (N + NWQ8 + NWO8 + 255) / 256;

    // prep: zero counts + split weights (one kernel)
    prep_kernel<<<npb, 256, 0, stream>>>(w_qkv, w_out, wq_hi, wq_lo, wo_hi, wo_lo, counts, N);
    // CSR build (by dst)
    hist_kernel     <<<neb, 256, 0, stream>>>(dst, counts, E);
    scan_partial_kernel<<<nb, 256, 0, stream>>>(counts, offsets, bsums, N);
    scan_sums_kernel<<<1, 256, 0, stream>>>(bsums, nb);
    scan_add_kernel <<<nb, 256, 0, stream>>>(offsets, bsums, cursor, N);
    scatter_kernel  <<<neb, 256, 0, stream>>>(src, dst, cursor, csr_src, E);

    // QKV projection (2-pass, inline bf16 conversion of x; packed q/k/v epilogue)
    qkv_gemm_kernel<<<dim3((N + TM - 1) / TM, NQKV / TN), 256, 0, stream>>>(
        x, wq_hi, wq_lo, b_qkv, qf, kbf, vbf, N);

    // wave-per-node attention (emits agg as bf16 hi/lo)
    wave_attn_kernel<<<(N + 3) / 4, 256, 0, stream>>>(
        qf, kbf, vbf, csr_src, offsets, counts, agg_hi, agg_lo, N);

    // output projection (3-pass split-bf16)
    out_gemm_kernel<<<dim3((N + TM - 1) / TM, 1), 256, 0, stream>>>(
        agg_hi, agg_lo, wo_hi, wo_lo, b_out, out, N);
}